// Round 12
// baseline (331.765 us; speedup 1.0000x reference)
//
#include <hip/hip_runtime.h>

// HellingerDistance: out[n][m] = 0.5*(rowsum_a[n] + rowsum_b[m]) - sqrt(a[n])·sqrt(b[m])
// N = M = 8192, D = 1024, f32 in/out.
// Round 12: FAT-WAVE GEMM. 256x256 tile, 4 waves (1/SIMD), each wave owns a
// 128x128 output (acc = 256 regs -> AGPRs via unified file). Fragment-read DS
// traffic drops 192->128 KB/K-tile; DS no longer the binding pipe. Per phase:
// 16 ds_reads + per-m lgkm ladder + 64 MFMA. Distance-2 staging ring, vmcnt(8)
// gates, both-sides XOR swizzle, bijective XCD swizzle.

#define NM 8192
#define DD 1024

typedef __attribute__((ext_vector_type(8))) short bf16x8;
typedef __attribute__((ext_vector_type(4))) float f32x4;

#define AS1 __attribute__((address_space(1)))
#define AS3 __attribute__((address_space(3)))

#define SCHED0 __builtin_amdgcn_sched_barrier(0)
#define WAIT_LGKM(n) do { SCHED0; asm volatile("s_waitcnt lgkmcnt(" #n ")" ::: "memory"); SCHED0; } while (0)
#define WAIT_VM(n)   do { SCHED0; asm volatile("s_waitcnt vmcnt(" #n ")" ::: "memory"); SCHED0; } while (0)
#define BAR __builtin_amdgcn_s_barrier()

// f32 -> bf16 round-to-nearest-even (inputs positive, no NaN/Inf)
static __device__ __forceinline__ unsigned short f2bf(float f) {
  unsigned int u = __float_as_uint(f);
  u += 0x7FFFu + ((u >> 16) & 1u);
  return (unsigned short)(u >> 16);
}

// ---------------- kernel 1: sqrt -> bf16, exact f32 rowsums ----------------
__global__ __launch_bounds__(256)
void hell_prep(const float* __restrict__ A, const float* __restrict__ B,
               unsigned short* __restrict__ SA, unsigned short* __restrict__ SB,
               float* __restrict__ RA, float* __restrict__ RB) {
  __shared__ float wsum[4];
  const int row = blockIdx.x & (NM - 1);
  const bool isB = blockIdx.x >= NM;
  const float* src = (isB ? B : A) + (size_t)row * DD;
  unsigned short* dst = (isB ? SB : SA) + (size_t)row * DD;
  const int t = threadIdx.x;
  const float4 v = ((const float4*)src)[t];
  ushort4 p;
  p.x = f2bf(sqrtf(v.x)); p.y = f2bf(sqrtf(v.y));
  p.z = f2bf(sqrtf(v.z)); p.w = f2bf(sqrtf(v.w));
  ((ushort4*)dst)[t] = p;
  float s = (v.x + v.y) + (v.z + v.w);
#pragma unroll
  for (int m = 1; m < 64; m <<= 1) s += __shfl_xor(s, m, 64);
  if ((t & 63) == 0) wsum[t >> 6] = s;
  __syncthreads();
  if (t == 0) (isB ? RB : RA)[row] = wsum[0] + wsum[1] + wsum[2] + wsum[3];
}

// ---------------- kernel 2: fat-wave 256^2 bf16 GEMM -----------------------
// LDS buf d at d*65536: A rows 0..255 (128B/row) at +0, B at +32768.
// Chunk c (16B) of row r stored at c ^ (r&7) (both-sides swizzle).
__global__ __launch_bounds__(256, 1)
void hell_gemm11(const unsigned short* __restrict__ SA,
                 const unsigned short* __restrict__ SB,
                 const float* __restrict__ RA, const float* __restrict__ RB,
                 float* __restrict__ C) {
  __shared__ __attribute__((aligned(16))) char lds[131072];

  const int t = threadIdx.x;
  const int lane = t & 63;
  const int wave = t >> 6;     // 0..3
  const int wm = wave >> 1;    // 0..1 -> rows wm*128
  const int wn = wave & 1;     // 0..1 -> cols wn*128

  // bijective XCD swizzle: nwg = 1024, 8 XCDs, chunk = 128
  const int wg = blockIdx.x;
  const int s = (wg & 7) * 128 + (wg >> 3);
  const int brow = (s >> 5) * 256;
  const int bcol = (s & 31) * 256;

  const int sw = ((t >> 3) & 7) ^ (t & 7);  // pre-swizzled source chunk

  const int hi = lane >> 4;
  const int lo = lane & 15;
  const int x7 = lo & 7;

  f32x4 acc[8][8];   // 256 regs -> AGPRs (unified file, 1 wave/SIMD)
#pragma unroll
  for (int m = 0; m < 8; ++m)
#pragma unroll
    for (int n = 0; n < 8; ++n) acc[m][n] = (f32x4){0.f, 0.f, 0.f, 0.f};

  bf16x8 af[8];    // A fragments, one k-half
  bf16x8 bfr[8];   // B fragments, one k-half

// stage one full 256x64 matrix tile: 8 gload_lds per thread (32 KB)
#define STAGE_MAT(MAT, BASE0, KT, LDSOFF)                                       \
  do {                                                                          \
    _Pragma("unroll")                                                           \
    for (int i_ = 0; i_ < 8; ++i_) {                                            \
      const unsigned short* g_ = (MAT) +                                        \
          (size_t)((BASE0) + i_ * 32 + (t >> 3)) * DD + (size_t)(KT) * 64 + sw * 8; \
      __builtin_amdgcn_global_load_lds((const AS1 unsigned int*)g_,             \
          (AS3 unsigned int*)(lds + (LDSOFF) + i_ * 4096 + t * 16), 16, 0, 0);  \
    }                                                                           \
  } while (0)

#define SA_T(KT, BUF) STAGE_MAT(SA, brow, KT, (BUF)*65536)
#define SB_T(KT, BUF) STAGE_MAT(SB, bcol, KT, (BUF)*65536 + 32768)

// issue order: B first (8), then A (8) — ladder counts depend on this
#define LDB8(BASE, kh)                                                          \
  do {                                                                          \
    _Pragma("unroll")                                                           \
    for (int n_ = 0; n_ < 8; ++n_)                                              \
      bfr[n_] = *(const bf16x8*)((BASE) + 32768 +                               \
          (wn * 128 + n_ * 16 + lo) * 128 + ((((kh)*4 + hi) ^ x7) << 4));       \
  } while (0)

#define LDA8(BASE, kh)                                                          \
  do {                                                                          \
    _Pragma("unroll")                                                           \
    for (int m_ = 0; m_ < 8; ++m_)                                              \
      af[m_] = *(const bf16x8*)((BASE) +                                        \
          (wm * 128 + m_ * 16 + lo) * 128 + ((((kh)*4 + hi) ^ x7) << 4));       \
  } while (0)

// burst m: 8 independent MFMAs (distinct acc[m][n]); needs bfr[0..7]+af[m]
#define FBURST(m_)                                                              \
  do {                                                                          \
    _Pragma("unroll")                                                           \
    for (int n_ = 0; n_ < 8; ++n_)                                              \
      acc[m_][n_] = __builtin_amdgcn_mfma_f32_16x16x32_bf16(                    \
          af[m_], bfr[n_], acc[m_][n_], 0, 0, 0);                               \
  } while (0)

// ladder: burst m gated on first 9+m reads (issue order B0..7, A0..7)
#define LADDER()                                                                \
  do {                                                                          \
    __builtin_amdgcn_s_setprio(1);                                              \
    WAIT_LGKM(7); FBURST(0);                                                    \
    WAIT_LGKM(6); FBURST(1);                                                    \
    WAIT_LGKM(5); FBURST(2);                                                    \
    WAIT_LGKM(4); FBURST(3);                                                    \
    WAIT_LGKM(3); FBURST(4);                                                    \
    WAIT_LGKM(2); FBURST(5);                                                    \
    WAIT_LGKM(1); FBURST(6);                                                    \
    WAIT_LGKM(0); FBURST(7);                                                    \
    __builtin_amdgcn_s_setprio(0);                                              \
  } while (0)

  const char* E = lds;           // buf0: even K-tiles
  const char* O = lds + 65536;   // buf1: odd K-tiles

  // prologue: stage tile0 (E.A + E.B), 16 outstanding
  SA_T(0, 0); SB_T(0, 0);

#pragma unroll 1
  for (int it = 0; it < 8; ++it) {
    const bool last = (it == 7);

    // P1: stage O.A(2it+1); gate E (drain to 8 = O.A); read E kh0; ladder
    SA_T(2 * it + 1, 1);
    WAIT_VM(8);
    BAR;
    LDB8(E, 0); LDA8(E, 0);
    LADDER();
    BAR;

    // P2: stage O.B(2it+1); read E kh1 (E already certified)
    SB_T(2 * it + 1, 1);
    LDB8(E, 1); LDA8(E, 1);
    LADDER();
    BAR;

    // P3: stage E'.A(2it+2); gate O (drain to 8 = E'.A); read O kh0
    if (!last) { SA_T(2 * it + 2, 0); WAIT_VM(8); }
    else       { WAIT_VM(0); }
    BAR;
    LDB8(O, 0); LDA8(O, 0);
    LADDER();
    BAR;

    // P4: stage E'.B(2it+2); read O kh1
    if (!last) SB_T(2 * it + 2, 0);
    LDB8(O, 1); LDA8(O, 1);
    LADDER();
    BAR;
  }

#undef LADDER
#undef FBURST
#undef LDA8
#undef LDB8
#undef SB_T
#undef SA_T
#undef STAGE_MAT

  // epilogue: C/D layout col=lane&15, row=(lane>>4)*4+j
  float hrb[8];
#pragma unroll
  for (int n = 0; n < 8; ++n)
    hrb[n] = 0.5f * RB[bcol + wn * 128 + n * 16 + lo];
#pragma unroll
  for (int m = 0; m < 8; ++m) {
    const int rbase = wm * 128 + m * 16 + hi * 4;
#pragma unroll
    for (int j = 0; j < 4; ++j) {
      const int row = rbase + j;
      const float ha = 0.5f * RA[brow + row];
      float* orow = C + (size_t)(brow + row) * NM + bcol;
#pragma unroll
      for (int n = 0; n < 8; ++n)
        orow[wn * 128 + n * 16 + lo] = ha + hrb[n] - acc[m][n][j];
    }
  }
}

// ---------------- fallback: fused kernel (if ws too small) -----------------
static __device__ __forceinline__ int swz(int row, int colbytes) {
  return (row * 128 + colbytes) ^ ((row & 7) << 4);
}

__global__ __launch_bounds__(256, 2)
void hellinger_fused(const float* __restrict__ A, const float* __restrict__ B,
                     float* __restrict__ C) {
  __shared__ unsigned short As[128 * 64];
  __shared__ unsigned short Bs[128 * 64];
  __shared__ float sA[128];
  __shared__ float sB[128];

  const int t = threadIdx.x;
  const int lane = t & 63;
  const int wave = t >> 6;
  const int wrow = (wave >> 1) * 64;
  const int wcol = (wave & 1) * 64;
  const int brow = blockIdx.y * 128;
  const int bcol = blockIdx.x * 128;
  const int sr = t >> 4;
  const int sc = (t & 15) * 4;

  const float* ap = A + (size_t)(brow + sr) * DD + sc;
  const float* bp = B + (size_t)(bcol + sr) * DD + sc;

  float racc[8], cacc[8];
#pragma unroll
  for (int i = 0; i < 8; ++i) { racc[i] = 0.f; cacc[i] = 0.f; }

  f32x4 acc[4][4];
#pragma unroll
  for (int m = 0; m < 4; ++m)
#pragma unroll
    for (int n = 0; n < 4; ++n) acc[m][n] = (f32x4){0.f, 0.f, 0.f, 0.f};

  for (int kt = 0; kt < DD / 64; ++kt) {
#pragma unroll
    for (int i = 0; i < 8; ++i) {
      const float4 v = *(const float4*)(ap + (size_t)(i * 16) * DD + kt * 64);
      racc[i] += (v.x + v.y) + (v.z + v.w);
      ushort4 p;
      p.x = f2bf(sqrtf(v.x)); p.y = f2bf(sqrtf(v.y));
      p.z = f2bf(sqrtf(v.z)); p.w = f2bf(sqrtf(v.w));
      *(ushort4*)((char*)As + swz(i * 16 + sr, sc * 2)) = p;
    }
#pragma unroll
    for (int i = 0; i < 8; ++i) {
      const float4 v = *(const float4*)(bp + (size_t)(i * 16) * DD + kt * 64);
      cacc[i] += (v.x + v.y) + (v.z + v.w);
      ushort4 p;
      p.x = f2bf(sqrtf(v.x)); p.y = f2bf(sqrtf(v.y));
      p.z = f2bf(sqrtf(v.z)); p.w = f2bf(sqrtf(v.w));
      *(ushort4*)((char*)Bs + swz(i * 16 + sr, sc * 2)) = p;
    }
    __syncthreads();
#pragma unroll
    for (int kk = 0; kk < 2; ++kk) {
      const int koffb = kk * 64 + (lane >> 4) * 16;
      bf16x8 af[4], bfr[4];
#pragma unroll
      for (int m = 0; m < 4; ++m)
        af[m] = *(const bf16x8*)((const char*)As + swz(wrow + m * 16 + (lane & 15), koffb));
#pragma unroll
      for (int n = 0; n < 4; ++n)
        bfr[n] = *(const bf16x8*)((const char*)Bs + swz(wcol + n * 16 + (lane & 15), koffb));
#pragma unroll
      for (int m = 0; m < 4; ++m)
#pragma unroll
        for (int n = 0; n < 4; ++n)
          acc[m][n] = __builtin_amdgcn_mfma_f32_16x16x32_bf16(af[m], bfr[n], acc[m][n], 0, 0, 0);
    }
    __syncthreads();
  }

#pragma unroll
  for (int i = 0; i < 8; ++i) {
#pragma unroll
    for (int mask = 1; mask < 16; mask <<= 1) {
      racc[i] += __shfl_xor(racc[i], mask, 64);
      cacc[i] += __shfl_xor(cacc[i], mask, 64);
    }
  }
  if ((t & 15) == 0) {
#pragma unroll
    for (int i = 0; i < 8; ++i) { sA[i * 16 + sr] = racc[i]; sB[i * 16 + sr] = cacc[i]; }
  }
  __syncthreads();

#pragma unroll
  for (int m = 0; m < 4; ++m) {
    const int rbase = wrow + m * 16 + (lane >> 4) * 4;
#pragma unroll
    for (int j = 0; j < 4; ++j) {
      const int row = rbase + j;
      const float ha = 0.5f * sA[row];
      float* orow = C + (size_t)(brow + row) * NM + bcol;
#pragma unroll
      for (int n = 0; n < 4; ++n) {
        const int col = wcol + n * 16 + (lane & 15);
        orow[col] = ha + 0.5f * sB[col] - acc[m][n][j];
      }
    }
  }
}

extern "C" void kernel_launch(void* const* d_in, const int* in_sizes, int n_in,
                              void* d_out, int out_size, void* d_ws, size_t ws_size,
                              hipStream_t stream) {
  const float* a = (const float*)d_in[0];
  const float* b = (const float*)d_in[1];
  float* out = (float*)d_out;

  const size_t mat_bytes = (size_t)NM * DD * sizeof(unsigned short); // 16 MB
  const size_t need = 2 * mat_bytes + 2 * (size_t)NM * sizeof(float);

  if (ws_size >= need) {
    unsigned short* SA = (unsigned short*)d_ws;
    unsigned short* SB = (unsigned short*)((char*)d_ws + mat_bytes);
    float* RA = (float*)((char*)d_ws + 2 * mat_bytes);
    float* RB = RA + NM;
    hipLaunchKernelGGL(hell_prep, dim3(2 * NM), dim3(256), 0, stream,
                       a, b, SA, SB, RA, RB);
    hipLaunchKernelGGL(hell_gemm11, dim3(32 * 32), dim3(256), 0, stream,
                       SA, SB, RA, RB, out);
  } else {
    dim3 grid(NM / 128, NM / 128);
    hipLaunchKernelGGL(hellinger_fused, grid, dim3(256), 0, stream, a, b, out);
  }
}

// Round 14
// 177.951 us; speedup vs baseline: 1.8644x; 1.8644x over previous
//
#include <hip/hip_runtime.h>

// HellingerDistance: out[n][m] = 0.5*(rowsum_a[n] + rowsum_b[m]) - sqrt(a[n])·sqrt(b[m])
// N = M = 8192, D = 1024, f32 in/out.
// Round 14: 32x32x16 MFMA (matrix pipe -17%, half the instructions) with the
// r7-proven ring restored: B-frags hoisted ONCE per K-tile (p1/p5) into regs
// so staging E'.B at p3/p4 never races B reads (r13's bug). ONE barrier per
// phase (stage-safety via post-MFMA BAR; VM(4) gates before the p4/p8 BAR).

#define NM 8192
#define DD 1024

typedef __attribute__((ext_vector_type(8))) short bf16x8;
typedef __attribute__((ext_vector_type(4))) float f32x4;
typedef __attribute__((ext_vector_type(16))) float f32x16;

#define AS1 __attribute__((address_space(1)))
#define AS3 __attribute__((address_space(3)))

#define SCHED0 __builtin_amdgcn_sched_barrier(0)
#define WAIT_LGKM0  do { SCHED0; asm volatile("s_waitcnt lgkmcnt(0)" ::: "memory"); SCHED0; } while (0)
#define WAIT_VM(n)  do { SCHED0; asm volatile("s_waitcnt vmcnt(" #n ")" ::: "memory"); SCHED0; } while (0)
#define BAR __builtin_amdgcn_s_barrier()

// f32 -> bf16 round-to-nearest-even (inputs positive, no NaN/Inf)
static __device__ __forceinline__ unsigned short f2bf(float f) {
  unsigned int u = __float_as_uint(f);
  u += 0x7FFFu + ((u >> 16) & 1u);
  return (unsigned short)(u >> 16);
}

// ---------------- kernel 1: sqrt -> bf16, exact f32 rowsums ----------------
__global__ __launch_bounds__(256)
void hell_prep(const float* __restrict__ A, const float* __restrict__ B,
               unsigned short* __restrict__ SA, unsigned short* __restrict__ SB,
               float* __restrict__ RA, float* __restrict__ RB) {
  __shared__ float wsum[4];
  const int row = blockIdx.x & (NM - 1);
  const bool isB = blockIdx.x >= NM;
  const float* src = (isB ? B : A) + (size_t)row * DD;
  unsigned short* dst = (isB ? SB : SA) + (size_t)row * DD;
  const int t = threadIdx.x;
  const float4 v = ((const float4*)src)[t];
  ushort4 p;
  p.x = f2bf(sqrtf(v.x)); p.y = f2bf(sqrtf(v.y));
  p.z = f2bf(sqrtf(v.z)); p.w = f2bf(sqrtf(v.w));
  ((ushort4*)dst)[t] = p;
  float s = (v.x + v.y) + (v.z + v.w);
#pragma unroll
  for (int m = 1; m < 64; m <<= 1) s += __shfl_xor(s, m, 64);
  if ((t & 63) == 0) wsum[t >> 6] = s;
  __syncthreads();
  if (t == 0) (isB ? RB : RA)[row] = wsum[0] + wsum[1] + wsum[2] + wsum[3];
}

// ---------------- kernel 2: 256^2 8-phase, 32x32x16 MFMA, B-in-regs --------
// LDS buf d at d*65536: A rows 0..255 (128B/row) at +0, B at +32768.
// Chunk c (16B) of row r stored at c ^ (r&7) (both-sides swizzle).
__global__ __launch_bounds__(512, 1)
void hell_gemm13(const unsigned short* __restrict__ SA,
                 const unsigned short* __restrict__ SB,
                 const float* __restrict__ RA, const float* __restrict__ RB,
                 float* __restrict__ C) {
  __shared__ __attribute__((aligned(16))) char lds[131072];

  const int t = threadIdx.x;
  const int lane = t & 63;
  const int wave = t >> 6;
  const int wm = wave >> 2;   // 0..1 -> rows wm*128
  const int wn = wave & 3;    // 0..3 -> cols wn*64

  // bijective XCD swizzle: nwg = 1024, 8 XCDs, chunk = 128
  const int wg = blockIdx.x;
  const int s = (wg & 7) * 128 + (wg >> 3);
  const int brow = (s >> 5) * 256;
  const int bcol = (s & 31) * 256;

  const int sw = ((t >> 3) & 7) ^ (t & 7);  // pre-swizzled source chunk

  const int hi2 = lane >> 5;   // k-group (0..1)
  const int lo5 = lane & 31;   // row/col within 32
  const int x7 = lane & 7;     // row&7 for swizzled reads (== lo5&7)

  f32x16 acc[4][2];            // 8 x 32x32 accum tiles = 128 regs
#pragma unroll
  for (int m = 0; m < 4; ++m)
#pragma unroll
    for (int n = 0; n < 2; ++n)
#pragma unroll
      for (int r = 0; r < 16; ++r) acc[m][n][r] = 0.f;

  bf16x8 af[4];      // A fragments, current k-step (4 m-tiles)
  bf16x8 bfr[2][4];  // B fragments, whole K-tile (2 n-tiles x 4 k-steps)

#define STAGE_HALF(MAT, BROW0, KT, LDSOFF)                                      \
  do {                                                                          \
    const unsigned short* g_ =                                                  \
        (MAT) + (size_t)((BROW0) + (t >> 3)) * DD + (size_t)(KT) * 64 + sw * 8; \
    __builtin_amdgcn_global_load_lds((const AS1 unsigned int*)g_,               \
        (AS3 unsigned int*)(lds + (LDSOFF) + t * 16), 16, 0, 0);                \
    __builtin_amdgcn_global_load_lds((const AS1 unsigned int*)(g_ + 64 * DD),   \
        (AS3 unsigned int*)(lds + (LDSOFF) + 8192 + t * 16), 16, 0, 0);         \
  } while (0)

#define SA_HALF(KT, BUF, H) STAGE_HALF(SA, brow + (H)*128, KT, (BUF)*65536 + (H)*16384)
#define SB_HALF(KT, BUF, H) STAGE_HALF(SB, bcol + (H)*128, KT, (BUF)*65536 + 32768 + (H)*16384)

// hoist ALL B fragments of a K-tile (8 ds_reads)
#define LDB_ALL(BASE)                                                           \
  do {                                                                          \
    _Pragma("unroll")                                                           \
    for (int n_ = 0; n_ < 2; ++n_)                                              \
      _Pragma("unroll")                                                         \
      for (int ks_ = 0; ks_ < 4; ++ks_)                                         \
        bfr[n_][ks_] = *(const bf16x8*)((BASE) + 32768 +                        \
            (wn * 64 + n_ * 32 + lo5) * 128 + ((((ks_)*2 + hi2) ^ x7) << 4));   \
  } while (0)

// A fragments for one k-step (4 ds_reads)
#define LDA4(BASE, ks)                                                          \
  do {                                                                          \
    _Pragma("unroll")                                                           \
    for (int m_ = 0; m_ < 4; ++m_)                                              \
      af[m_] = *(const bf16x8*)((BASE) +                                        \
          (wm * 128 + m_ * 32 + lo5) * 128 + ((((ks)*2 + hi2) ^ x7) << 4));     \
  } while (0)

// 8 independent 32x32x16 MFMAs (distinct acc tiles)
#define MFMA8(ks)                                                               \
  do {                                                                          \
    __builtin_amdgcn_s_setprio(1);                                              \
    _Pragma("unroll")                                                           \
    for (int m_ = 0; m_ < 4; ++m_)                                              \
      _Pragma("unroll")                                                         \
      for (int n_ = 0; n_ < 2; ++n_)                                            \
        acc[m_][n_] = __builtin_amdgcn_mfma_f32_32x32x16_bf16(                  \
            af[m_], bfr[n_][ks], acc[m_][n_], 0, 0, 0);                         \
    __builtin_amdgcn_s_setprio(0);                                              \
  } while (0)

  const char* E = lds;           // buf0: even K-tiles
  const char* O = lds + 65536;   // buf1: odd K-tiles

  // prologue: stage tile0 full (E) + tile1 B (O); wait tile0, t1.B in flight
  SA_HALF(0, 0, 0); SA_HALF(0, 0, 1);
  SB_HALF(0, 0, 0); SB_HALF(0, 0, 1);
  SB_HALF(1, 1, 0); SB_HALF(1, 1, 1);
  WAIT_VM(4);
  BAR;

#pragma unroll 1
  for (int it = 0; it < 8; ++it) {
    const int last = (it == 7);
    // p1: hoist E.B + E.A ks0; stage odd.A(2it+1) h0
    LDB_ALL(E); LDA4(E, 0);
    SA_HALF(2 * it + 1, 1, 0);
    WAIT_LGKM0; MFMA8(0); BAR;
    // p2: E ks1; stage odd.A h1
    LDA4(E, 1);
    SA_HALF(2 * it + 1, 1, 1);
    WAIT_LGKM0; MFMA8(1); BAR;
    // p3: E ks2; stage even.B(2it+2) h0 (E.B reads done since p1's BAR)
    LDA4(E, 2);
    if (!last) SB_HALF(2 * it + 2, 0, 0);
    WAIT_LGKM0; MFMA8(2); BAR;
    // p4: E ks3; stage even.B h1; gate: odd tile (O.A p1/p2 + O.B prev p7/p8)
    LDA4(E, 3);
    if (!last) SB_HALF(2 * it + 2, 0, 1);
    WAIT_LGKM0; MFMA8(3);
    if (!last) WAIT_VM(4); else WAIT_VM(0);
    BAR;
    // p5: hoist O.B + O.A ks0; stage even.A(2it+2) h0 (E.A reads done at p4 BAR)
    LDB_ALL(O); LDA4(O, 0);
    if (!last) SA_HALF(2 * it + 2, 0, 0);
    WAIT_LGKM0; MFMA8(0); BAR;
    // p6: O ks1; stage even.A h1
    LDA4(O, 1);
    if (!last) SA_HALF(2 * it + 2, 0, 1);
    WAIT_LGKM0; MFMA8(1); BAR;
    // p7: O ks2; stage odd.B(2it+3) h0 (O.B reads done since p5's BAR)
    LDA4(O, 2);
    if (!last) SB_HALF(2 * it + 3, 1, 0);
    WAIT_LGKM0; MFMA8(2); BAR;
    // p8: O ks3; stage odd.B h1; gate: even tile (E'.B p3/p4 + E'.A p5/p6)
    LDA4(O, 3);
    if (!last) SB_HALF(2 * it + 3, 1, 1);
    WAIT_LGKM0; MFMA8(3);
    if (!last) { WAIT_VM(4); }
    BAR;
  }

#undef MFMA8
#undef LDA4
#undef LDB_ALL
#undef SB_HALF
#undef SA_HALF
#undef STAGE_HALF

  // epilogue: 32x32 C/D layout col=lane&31, row=(r&3)+8*(r>>2)+4*(lane>>5)
  float hrb[2];
#pragma unroll
  for (int n = 0; n < 2; ++n)
    hrb[n] = 0.5f * RB[bcol + wn * 64 + n * 32 + lo5];
#pragma unroll
  for (int m = 0; m < 4; ++m) {
#pragma unroll
    for (int r = 0; r < 16; ++r) {
      const int row = (r & 3) + 8 * (r >> 2) + 4 * hi2;
      const int R = wm * 128 + m * 32 + row;
      const float ha = 0.5f * RA[brow + R];
      float* orow = C + (size_t)(brow + R) * NM + bcol;
#pragma unroll
      for (int n = 0; n < 2; ++n)
        orow[wn * 64 + n * 32 + lo5] = ha + hrb[n] - acc[m][n][r];
    }
  }
}

// ---------------- fallback: fused kernel (if ws too small) -----------------
static __device__ __forceinline__ int swz(int row, int colbytes) {
  return (row * 128 + colbytes) ^ ((row & 7) << 4);
}

__global__ __launch_bounds__(256, 2)
void hellinger_fused(const float* __restrict__ A, const float* __restrict__ B,
                     float* __restrict__ C) {
  __shared__ unsigned short As[128 * 64];
  __shared__ unsigned short Bs[128 * 64];
  __shared__ float sA[128];
  __shared__ float sB[128];

  const int t = threadIdx.x;
  const int lane = t & 63;
  const int wave = t >> 6;
  const int wrow = (wave >> 1) * 64;
  const int wcol = (wave & 1) * 64;
  const int brow = blockIdx.y * 128;
  const int bcol = blockIdx.x * 128;
  const int sr = t >> 4;
  const int sc = (t & 15) * 4;

  const float* ap = A + (size_t)(brow + sr) * DD + sc;
  const float* bp = B + (size_t)(bcol + sr) * DD + sc;

  float racc[8], cacc[8];
#pragma unroll
  for (int i = 0; i < 8; ++i) { racc[i] = 0.f; cacc[i] = 0.f; }

  f32x4 acc[4][4];
#pragma unroll
  for (int m = 0; m < 4; ++m)
#pragma unroll
    for (int n = 0; n < 4; ++n) acc[m][n] = (f32x4){0.f, 0.f, 0.f, 0.f};

  for (int kt = 0; kt < DD / 64; ++kt) {
#pragma unroll
    for (int i = 0; i < 8; ++i) {
      const float4 v = *(const float4*)(ap + (size_t)(i * 16) * DD + kt * 64);
      racc[i] += (v.x + v.y) + (v.z + v.w);
      ushort4 p;
      p.x = f2bf(sqrtf(v.x)); p.y = f2bf(sqrtf(v.y));
      p.z = f2bf(sqrtf(v.z)); p.w = f2bf(sqrtf(v.w));
      *(ushort4*)((char*)As + swz(i * 16 + sr, sc * 2)) = p;
    }
#pragma unroll
    for (int i = 0; i < 8; ++i) {
      const float4 v = *(const float4*)(bp + (size_t)(i * 16) * DD + kt * 64);
      cacc[i] += (v.x + v.y) + (v.z + v.w);
      ushort4 p;
      p.x = f2bf(sqrtf(v.x)); p.y = f2bf(sqrtf(v.y));
      p.z = f2bf(sqrtf(v.z)); p.w = f2bf(sqrtf(v.w));
      *(ushort4*)((char*)Bs + swz(i * 16 + sr, sc * 2)) = p;
    }
    __syncthreads();
#pragma unroll
    for (int kk = 0; kk < 2; ++kk) {
      const int koffb = kk * 64 + (lane >> 4) * 16;
      bf16x8 af[4], bfr[4];
#pragma unroll
      for (int m = 0; m < 4; ++m)
        af[m] = *(const bf16x8*)((const char*)As + swz(wrow + m * 16 + (lane & 15), koffb));
#pragma unroll
      for (int n = 0; n < 4; ++n)
        bfr[n] = *(const bf16x8*)((const char*)Bs + swz(wcol + n * 16 + (lane & 15), koffb));
#pragma unroll
      for (int m = 0; m < 4; ++m)
#pragma unroll
        for (int n = 0; n < 4; ++n)
          acc[m][n] = __builtin_amdgcn_mfma_f32_16x16x32_bf16(af[m], bfr[n], acc[m][n], 0, 0, 0);
    }
    __syncthreads();
  }

#pragma unroll
  for (int i = 0; i < 8; ++i) {
#pragma unroll
    for (int mask = 1; mask < 16; mask <<= 1) {
      racc[i] += __shfl_xor(racc[i], mask, 64);
      cacc[i] += __shfl_xor(cacc[i], mask, 64);
    }
  }
  if ((t & 15) == 0) {
#pragma unroll
    for (int i = 0; i < 8; ++i) { sA[i * 16 + sr] = racc[i]; sB[i * 16 + sr] = cacc[i]; }
  }
  __syncthreads();

#pragma unroll
  for (int m = 0; m < 4; ++m) {
    const int rbase = wrow + m * 16 + (lane >> 4) * 4;
#pragma unroll
    for (int j = 0; j < 4; ++j) {
      const int row = rbase + j;
      const float ha = 0.5f * sA[row];
      float* orow = C + (size_t)(brow + row) * NM + bcol;
#pragma unroll
      for (int n = 0; n < 4; ++n) {
        const int col = wcol + n * 16 + (lane & 15);
        orow[col] = ha + 0.5f * sB[col] - acc[m][n][j];
      }
    }
  }
}

extern "C" void kernel_launch(void* const* d_in, const int* in_sizes, int n_in,
                              void* d_out, int out_size, void* d_ws, size_t ws_size,
                              hipStream_t stream) {
  const float* a = (const float*)d_in[0];
  const float* b = (const float*)d_in[1];
  float* out = (float*)d_out;

  const size_t mat_bytes = (size_t)NM * DD * sizeof(unsigned short); // 16 MB
  const size_t need = 2 * mat_bytes + 2 * (size_t)NM * sizeof(float);

  if (ws_size >= need) {
    unsigned short* SA = (unsigned short*)d_ws;
    unsigned short* SB = (unsigned short*)((char*)d_ws + mat_bytes);
    float* RA = (float*)((char*)d_ws + 2 * mat_bytes);
    float* RB = RA + NM;
    hipLaunchKernelGGL(hell_prep, dim3(2 * NM), dim3(256), 0, stream,
                       a, b, SA, SB, RA, RB);
    hipLaunchKernelGGL(hell_gemm13, dim3(32 * 32), dim3(512), 0, stream,
                       SA, SB, RA, RB, out);
  } else {
    dim3 grid(NM / 128, NM / 128);
    hipLaunchKernelGGL(hellinger_fused, grid, dim3(256), 0, stream, a, b, out);
  }
}

// Round 15
// 170.223 us; speedup vs baseline: 1.9490x; 1.0454x over previous
//
#include <hip/hip_runtime.h>

// HellingerDistance: out[n][m] = 0.5*(rowsum_a[n] + rowsum_b[m]) - sqrt(a[n])·sqrt(b[m])
// N = M = 8192, D = 1024, f32 in/out.
// Round 15: r7's conflict-free 16x16 fragment pattern + ONE-PHASE-AHEAD reads.
// Phases = k-half x m-half (4/K-tile, 16 MFMA each). Two A-sets + two B-half-
// sets ping-pong (+16 regs vs r7 — exactly the measured headroom). Only phase-1
// reads are exposed; e2-e4 consume registers read one phase earlier, so the DS
// pipe runs UNDER the MFMA bursts. Ring/gates byte-identical to r7.

#define NM 8192
#define DD 1024

typedef __attribute__((ext_vector_type(8))) short bf16x8;
typedef __attribute__((ext_vector_type(4))) float f32x4;

#define AS1 __attribute__((address_space(1)))
#define AS3 __attribute__((address_space(3)))

#define SCHED0 __builtin_amdgcn_sched_barrier(0)
#define WAIT_LGKM(n) do { SCHED0; asm volatile("s_waitcnt lgkmcnt(" #n ")" ::: "memory"); SCHED0; } while (0)
#define WAIT_VM(n)   do { SCHED0; asm volatile("s_waitcnt vmcnt(" #n ")" ::: "memory"); SCHED0; } while (0)
#define BAR __builtin_amdgcn_s_barrier()

// f32 -> bf16 round-to-nearest-even (inputs positive, no NaN/Inf)
static __device__ __forceinline__ unsigned short f2bf(float f) {
  unsigned int u = __float_as_uint(f);
  u += 0x7FFFu + ((u >> 16) & 1u);
  return (unsigned short)(u >> 16);
}

// ---------------- kernel 1: sqrt -> bf16, exact f32 rowsums ----------------
__global__ __launch_bounds__(256)
void hell_prep(const float* __restrict__ A, const float* __restrict__ B,
               unsigned short* __restrict__ SA, unsigned short* __restrict__ SB,
               float* __restrict__ RA, float* __restrict__ RB) {
  __shared__ float wsum[4];
  const int row = blockIdx.x & (NM - 1);
  const bool isB = blockIdx.x >= NM;
  const float* src = (isB ? B : A) + (size_t)row * DD;
  unsigned short* dst = (isB ? SB : SA) + (size_t)row * DD;
  const int t = threadIdx.x;
  const float4 v = ((const float4*)src)[t];
  ushort4 p;
  p.x = f2bf(sqrtf(v.x)); p.y = f2bf(sqrtf(v.y));
  p.z = f2bf(sqrtf(v.z)); p.w = f2bf(sqrtf(v.w));
  ((ushort4*)dst)[t] = p;
  float s = (v.x + v.y) + (v.z + v.w);
#pragma unroll
  for (int m = 1; m < 64; m <<= 1) s += __shfl_xor(s, m, 64);
  if ((t & 63) == 0) wsum[t >> 6] = s;
  __syncthreads();
  if (t == 0) (isB ? RB : RA)[row] = wsum[0] + wsum[1] + wsum[2] + wsum[3];
}

// ---------------- kernel 2: 256^2, read-ahead 16x16 pipeline ---------------
// LDS buf d at d*65536: A rows 0..255 (128B/row) at +0, B at +32768.
// Chunk c (16B) of row r stored at c ^ (r&7) (both-sides swizzle).
__global__ __launch_bounds__(512, 1)
void hell_gemm14(const unsigned short* __restrict__ SA,
                 const unsigned short* __restrict__ SB,
                 const float* __restrict__ RA, const float* __restrict__ RB,
                 float* __restrict__ C) {
  __shared__ __attribute__((aligned(16))) char lds[131072];

  const int t = threadIdx.x;
  const int lane = t & 63;
  const int wave = t >> 6;
  const int wm = wave >> 2;   // 0..1 -> rows wm*128
  const int wn = wave & 3;    // 0..3 -> cols wn*64

  // bijective XCD swizzle: nwg = 1024, 8 XCDs, chunk = 128
  const int wg = blockIdx.x;
  const int s = (wg & 7) * 128 + (wg >> 3);
  const int brow = (s >> 5) * 256;
  const int bcol = (s & 31) * 256;

  const int sw = ((t >> 3) & 7) ^ (t & 7);  // pre-swizzled source chunk

  const int hi = lane >> 4;   // 0..3 (chunk sub-index — r7's conflict-free map)
  const int lo = lane & 15;   // fragment row within 16
  const int x7 = lo & 7;

  f32x4 acc[8][4];
#pragma unroll
  for (int m = 0; m < 8; ++m)
#pragma unroll
    for (int n = 0; n < 4; ++n) acc[m][n] = (f32x4){0.f, 0.f, 0.f, 0.f};

  bf16x8 afA[4], afB[4];     // A sets (m-half), ping-pong one phase ahead
  bf16x8 bfrA[4], bfrB[4];   // B half-sets (k-half 0 / 1)

#define STAGE_HALF(MAT, BROW0, KT, LDSOFF)                                      \
  do {                                                                          \
    const unsigned short* g_ =                                                  \
        (MAT) + (size_t)((BROW0) + (t >> 3)) * DD + (size_t)(KT) * 64 + sw * 8; \
    __builtin_amdgcn_global_load_lds((const AS1 unsigned int*)g_,               \
        (AS3 unsigned int*)(lds + (LDSOFF) + t * 16), 16, 0, 0);                \
    __builtin_amdgcn_global_load_lds((const AS1 unsigned int*)(g_ + 64 * DD),   \
        (AS3 unsigned int*)(lds + (LDSOFF) + 8192 + t * 16), 16, 0, 0);         \
  } while (0)

#define SA_HALF(KT, BUF, H) STAGE_HALF(SA, brow + (H)*128, KT, (BUF)*65536 + (H)*16384)
#define SB_HALF(KT, BUF, H) STAGE_HALF(SB, bcol + (H)*128, KT, (BUF)*65536 + 32768 + (H)*16384)

// 4 B-fragment reads, one k-half (r7 chunk map: (ks*4+hi)^x7)
#define LDB4(SET, BASE, ks)                                                     \
  do {                                                                          \
    _Pragma("unroll")                                                           \
    for (int n_ = 0; n_ < 4; ++n_)                                              \
      SET[n_] = *(const bf16x8*)((BASE) + 32768 +                               \
          (wn * 64 + n_ * 16 + lo) * 128 + ((((ks)*4 + hi) ^ x7) << 4));        \
  } while (0)

// 4 A-fragment reads, one k-half, one m-half (mg)
#define LDA4(SET, BASE, ks, mg)                                                 \
  do {                                                                          \
    _Pragma("unroll")                                                           \
    for (int m_ = 0; m_ < 4; ++m_)                                              \
      SET[m_] = *(const bf16x8*)((BASE) +                                       \
          (wm * 128 + ((mg)*4 + m_) * 16 + lo) * 128 +                          \
          ((((ks)*4 + hi) ^ x7) << 4));                                         \
  } while (0)

// 16 independent MFMAs: m-half mg x all n, one k-half
#define MFMA16(mg, ASET, BSET)                                                  \
  do {                                                                          \
    __builtin_amdgcn_s_setprio(1);                                              \
    _Pragma("unroll")                                                           \
    for (int m_ = 0; m_ < 4; ++m_)                                              \
      _Pragma("unroll")                                                         \
      for (int n_ = 0; n_ < 4; ++n_)                                            \
        acc[(mg)*4 + m_][n_] = __builtin_amdgcn_mfma_f32_16x16x32_bf16(         \
            ASET[m_], BSET[n_], acc[(mg)*4 + m_][n_], 0, 0, 0);                 \
    __builtin_amdgcn_s_setprio(0);                                              \
  } while (0)

  const char* E = lds;           // buf0: even K-tiles
  const char* O = lds + 65536;   // buf1: odd K-tiles

  // prologue: stage tile0 full (E) + tile1 B (O); wait tile0, t1.B in flight
  SA_HALF(0, 0, 0); SA_HALF(0, 0, 1);
  SB_HALF(0, 0, 0); SB_HALF(0, 0, 1);
  SB_HALF(1, 1, 0); SB_HALF(1, 1, 1);
  WAIT_VM(4);
  BAR;

#pragma unroll 1
  for (int it = 0; it < 8; ++it) {
    const int last = (it == 7);

    // ---- tile E (kt = 2it) ----
    // e1: B(ks0)+A(ks0,mlo)+A(ks0,mhi); stage O.Ah0; lgkm(4)->B+afA landed
    LDB4(bfrA, E, 0); LDA4(afA, E, 0, 0); LDA4(afB, E, 0, 1);
    SA_HALF(2 * it + 1, 1, 0);
    WAIT_LGKM(4); MFMA16(0, afA, bfrA); BAR;
    // e2: B(ks1)+A(ks1,mlo); stage O.Ah1; lgkm(4)->afB+bfrB landed (bfrB drained pre-BAR)
    LDB4(bfrB, E, 1); LDA4(afA, E, 1, 0);
    SA_HALF(2 * it + 1, 1, 1);
    WAIT_LGKM(4); MFMA16(1, afB, bfrA); BAR;
    // e3: A(ks1,mhi); stage E'.Bh0 (E.B reads drained at e1/e2); lgkm(4)->afA
    LDA4(afB, E, 1, 1);
    if (!last) SB_HALF(2 * it + 2, 0, 0);
    WAIT_LGKM(4); MFMA16(0, afA, bfrB); BAR;
    // e4: pure MFMA; stage E'.Bh1; gate O (O.A e1/e2 + O.B prev o3/o4 landed)
    if (!last) SB_HALF(2 * it + 2, 0, 1);
    WAIT_LGKM(0); MFMA16(1, afB, bfrB);
    if (!last) WAIT_VM(4); else WAIT_VM(0);
    BAR;

    // ---- tile O (kt = 2it+1) ----
    // o1: B(ks0)+A(ks0,mlo)+A(ks0,mhi); stage E'.Ah0 (E.A reads drained at e4)
    LDB4(bfrA, O, 0); LDA4(afA, O, 0, 0); LDA4(afB, O, 0, 1);
    if (!last) SA_HALF(2 * it + 2, 0, 0);
    WAIT_LGKM(4); MFMA16(0, afA, bfrA); BAR;
    // o2: B(ks1)+A(ks1,mlo); stage E'.Ah1
    LDB4(bfrB, O, 1); LDA4(afA, O, 1, 0);
    if (!last) SA_HALF(2 * it + 2, 0, 1);
    WAIT_LGKM(4); MFMA16(1, afB, bfrA); BAR;
    // o3: A(ks1,mhi); stage O'.Bh0 (O.B reads drained at o1/o2)
    LDA4(afB, O, 1, 1);
    if (!last) SB_HALF(2 * it + 3, 1, 0);
    WAIT_LGKM(4); MFMA16(0, afA, bfrB); BAR;
    // o4: pure MFMA; stage O'.Bh1; gate E' (E'.B e3/e4 + E'.A o1/o2 landed)
    if (!last) SB_HALF(2 * it + 3, 1, 1);
    WAIT_LGKM(0); MFMA16(1, afB, bfrB);
    if (!last) WAIT_VM(4);
    BAR;
  }

#undef MFMA16
#undef LDA4
#undef LDB4
#undef SB_HALF
#undef SA_HALF
#undef STAGE_HALF

  // epilogue: C/D layout col=lane&15, row=(lane>>4)*4+j
  float hrb[4];
#pragma unroll
  for (int n = 0; n < 4; ++n)
    hrb[n] = 0.5f * RB[bcol + wn * 64 + n * 16 + lo];
#pragma unroll
  for (int m = 0; m < 8; ++m) {
    const int rbase = wm * 128 + m * 16 + hi * 4;
#pragma unroll
    for (int j = 0; j < 4; ++j) {
      const int row = rbase + j;
      const float ha = 0.5f * RA[brow + row];
      float* orow = C + (size_t)(brow + row) * NM + bcol;
#pragma unroll
      for (int n = 0; n < 4; ++n)
        orow[wn * 64 + n * 16 + lo] = ha + hrb[n] - acc[m][n][j];
    }
  }
}

// ---------------- fallback: fused kernel (if ws too small) -----------------
static __device__ __forceinline__ int swz(int row, int colbytes) {
  return (row * 128 + colbytes) ^ ((row & 7) << 4);
}

__global__ __launch_bounds__(256, 2)
void hellinger_fused(const float* __restrict__ A, const float* __restrict__ B,
                     float* __restrict__ C) {
  __shared__ unsigned short As[128 * 64];
  __shared__ unsigned short Bs[128 * 64];
  __shared__ float sA[128];
  __shared__ float sB[128];

  const int t = threadIdx.x;
  const int lane = t & 63;
  const int wave = t >> 6;
  const int wrow = (wave >> 1) * 64;
  const int wcol = (wave & 1) * 64;
  const int brow = blockIdx.y * 128;
  const int bcol = blockIdx.x * 128;
  const int sr = t >> 4;
  const int sc = (t & 15) * 4;

  const float* ap = A + (size_t)(brow + sr) * DD + sc;
  const float* bp = B + (size_t)(bcol + sr) * DD + sc;

  float racc[8], cacc[8];
#pragma unroll
  for (int i = 0; i < 8; ++i) { racc[i] = 0.f; cacc[i] = 0.f; }

  f32x4 acc[4][4];
#pragma unroll
  for (int m = 0; m < 4; ++m)
#pragma unroll
    for (int n = 0; n < 4; ++n) acc[m][n] = (f32x4){0.f, 0.f, 0.f, 0.f};

  for (int kt = 0; kt < DD / 64; ++kt) {
#pragma unroll
    for (int i = 0; i < 8; ++i) {
      const float4 v = *(const float4*)(ap + (size_t)(i * 16) * DD + kt * 64);
      racc[i] += (v.x + v.y) + (v.z + v.w);
      ushort4 p;
      p.x = f2bf(sqrtf(v.x)); p.y = f2bf(sqrtf(v.y));
      p.z = f2bf(sqrtf(v.z)); p.w = f2bf(sqrtf(v.w));
      *(ushort4*)((char*)As + swz(i * 16 + sr, sc * 2)) = p;
    }
#pragma unroll
    for (int i = 0; i < 8; ++i) {
      const float4 v = *(const float4*)(bp + (size_t)(i * 16) * DD + kt * 64);
      cacc[i] += (v.x + v.y) + (v.z + v.w);
      ushort4 p;
      p.x = f2bf(sqrtf(v.x)); p.y = f2bf(sqrtf(v.y));
      p.z = f2bf(sqrtf(v.z)); p.w = f2bf(sqrtf(v.w));
      *(ushort4*)((char*)Bs + swz(i * 16 + sr, sc * 2)) = p;
    }
    __syncthreads();
#pragma unroll
    for (int kk = 0; kk < 2; ++kk) {
      const int koffb = kk * 64 + (lane >> 4) * 16;
      bf16x8 af[4], bfr[4];
#pragma unroll
      for (int m = 0; m < 4; ++m)
        af[m] = *(const bf16x8*)((const char*)As + swz(wrow + m * 16 + (lane & 15), koffb));
#pragma unroll
      for (int n = 0; n < 4; ++n)
        bfr[n] = *(const bf16x8*)((const char*)Bs + swz(wcol + n * 16 + (lane & 15), koffb));
#pragma unroll
      for (int m = 0; m < 4; ++m)
#pragma unroll
        for (int n = 0; n < 4; ++n)
          acc[m][n] = __builtin_amdgcn_mfma_f32_16x16x32_bf16(af[m], bfr[n], acc[m][n], 0, 0, 0);
    }
    __syncthreads();
  }

#pragma unroll
  for (int i = 0; i < 8; ++i) {
#pragma unroll
    for (int mask = 1; mask < 16; mask <<= 1) {
      racc[i] += __shfl_xor(racc[i], mask, 64);
      cacc[i] += __shfl_xor(cacc[i], mask, 64);
    }
  }
  if ((t & 15) == 0) {
#pragma unroll
    for (int i = 0; i < 8; ++i) { sA[i * 16 + sr] = racc[i]; sB[i * 16 + sr] = cacc[i]; }
  }
  __syncthreads();

#pragma unroll
  for (int m = 0; m < 4; ++m) {
    const int rbase = wrow + m * 16 + (lane >> 4) * 4;
#pragma unroll
    for (int j = 0; j < 4; ++j) {
      const int row = rbase + j;
      const float ha = 0.5f * sA[row];
      float* orow = C + (size_t)(brow + row) * NM + bcol;
#pragma unroll
      for (int n = 0; n < 4; ++n) {
        const int col = wcol + n * 16 + (lane & 15);
        orow[col] = ha + 0.5f * sB[col] - acc[m][n][j];
      }
    }
  }
}

extern "C" void kernel_launch(void* const* d_in, const int* in_sizes, int n_in,
                              void* d_out, int out_size, void* d_ws, size_t ws_size,
                              hipStream_t stream) {
  const float* a = (const float*)d_in[0];
  const float* b = (const float*)d_in[1];
  float* out = (float*)d_out;

  const size_t mat_bytes = (size_t)NM * DD * sizeof(unsigned short); // 16 MB
  const size_t need = 2 * mat_bytes + 2 * (size_t)NM * sizeof(float);

  if (ws_size >= need) {
    unsigned short* SA = (unsigned short*)d_ws;
    unsigned short* SB = (unsigned short*)((char*)d_ws + mat_bytes);
    float* RA = (float*)((char*)d_ws + 2 * mat_bytes);
    float* RB = RA + NM;
    hipLaunchKernelGGL(hell_prep, dim3(2 * NM), dim3(256), 0, stream,
                       a, b, SA, SB, RA, RB);
    hipLaunchKernelGGL(hell_gemm14, dim3(32 * 32), dim3(512), 0, stream,
                       SA, SB, RA, RB, out);
  } else {
    dim3 grid(NM / 128, NM / 128);
    hipLaunchKernelGGL(hellinger_fused, grid, dim3(256), 0, stream, a, b, out);
  }
}